// Round 5
// baseline (347.753 us; speedup 1.0000x reference)
//
#include <hip/hip_runtime.h>
#include <hip/hip_bf16.h>
#include <stdint.h>

#define BATCH   65536
#define UNITS   256
#define NCHUNK  8
#define ROWP    68                     // shorts per column in gate buffer
#define GSZ     (64 * ROWP)            // 4352 shorts per gate
#define SMEM_BYTES 34816               // max(A dbuf 16384, G 4*GSZ*2 = 34816)

using f32x16 = __attribute__((ext_vector_type(16))) float;
using bf16x8 = __attribute__((ext_vector_type(8))) short;

__device__ __forceinline__ short f2bf(float f) {
  union { float f; unsigned u; } v; v.f = f;
  unsigned r = v.u + 0x7FFFu + ((v.u >> 16) & 1u);   // RNE (prepass only)
  return (short)(r >> 16);
}
__device__ __forceinline__ float bf2f(short s) {
  union { float f; unsigned u; } v; v.u = ((unsigned)(unsigned short)s) << 16;
  return v.f;
}
__device__ __forceinline__ unsigned pk2(float a, float b) {   // v_cvt_pk_bf16_f32
  union { __hip_bfloat162 h; unsigned u; } cv;
  cv.h = __float22bfloat162_rn(make_float2(a, b));
  return cv.u;
}
__device__ __forceinline__ bf16x8 cvt8(float4 a, float4 b) {
  union { unsigned u[4]; bf16x8 v; } r;
  r.u[0] = pk2(a.x, a.y); r.u[1] = pk2(a.z, a.w);
  r.u[2] = pk2(b.x, b.y); r.u[3] = pk2(b.z, b.w);
  return r.v;
}

#define BAR() do { asm volatile("s_waitcnt lgkmcnt(0)" ::: "memory"); \
                   __builtin_amdgcn_s_barrier(); } while (0)

// ---- prepass: W_g fp32 [512][256] -> Wt bf16 tiled [g][nb][c][kg][n][k8]
__global__ void cvt_weights(const float* __restrict__ Wf, const float* __restrict__ Wi,
                            const float* __restrict__ Wc, const float* __restrict__ Wo,
                            short* __restrict__ Wt) {
  int idx = blockIdx.x * 256 + threadIdx.x;
  int g   = idx >> 17;
  int k   = (idx >> 8) & 511;
  int col = idx & 255;
  const float* W = (g == 0) ? Wf : (g == 1) ? Wi : (g == 2) ? Wc : Wo;
  float val = W[k * 256 + col];
  int nb = col >> 6, n = col & 63;
  int c = k >> 6, kg = (k >> 3) & 7, k8 = k & 7;
  int out = ((((g * 4 + nb) * 8 + c) * 8 + kg) * 64 + n) * 8 + k8;
  Wt[out] = f2bf(val);
}

// ---- fused LSTM cell: 4 waves/block, wave = gate; A LDS dbuf, B reg dbuf
// prefetched one chunk ahead (issued BEFORE the HBM A prefetch so vmcnt
// waits never drain in-flight HBM loads); counted-wait barriers; 4 blocks/CU.
__global__ __launch_bounds__(256, 4) void lstm_fused(
    const float* __restrict__ x, const float* __restrict__ hprev,
    const float* __restrict__ cprev, const short* __restrict__ Wt,
    const float* __restrict__ bfp, const float* __restrict__ bip,
    const float* __restrict__ bcp, const float* __restrict__ bop,
    float* __restrict__ hout, float* __restrict__ cout)
{
  extern __shared__ __align__(16) char smem[];
  const int tid  = threadIdx.x;
  const int g    = tid >> 6;           // wave = gate
  const int lane = tid & 63;
  const int la   = lane & 31;
  const int hh   = lane >> 5;

  int bid = blockIdx.x;
  int wg  = (bid & 7) * 512 + (bid >> 3);      // XCD-bijective swizzle
  const int m0 = (wg >> 2) * 64;
  const int nb = wg & 3;
  const int n0 = nb * 64;

  const short* Bbase = Wt + ((size_t)(g * 4 + nb)) * 32768 + hh * 512 + la * 8;

  f32x16 acc[2][2] = {};
  bf16x8 bregA[8], bregB[8];
  float4 v[4];

  const int arow  = tid >> 2;
  const int q     = tid & 3;
  const int slotW = (arow ^ (q << 2)) & 63;

  auto ldA = [&](int c) {
    const float* base = (c < 4) ? x : hprev;
    const float* rowp = base + (size_t)(m0 + arow) * 256 + (c & 3) * 64;
    v[0] = *(const float4*)(rowp + q * 8);
    v[1] = *(const float4*)(rowp + q * 8 + 4);
    v[2] = *(const float4*)(rowp + (q + 4) * 8);
    v[3] = *(const float4*)(rowp + (q + 4) * 8 + 4);
  };
  auto wrA = [&](int buf) {
    char* Ab = smem + buf * 8192;
    *(bf16x8*)(Ab + q * 1024 + slotW * 16)       = cvt8(v[0], v[1]);
    *(bf16x8*)(Ab + (q + 4) * 1024 + slotW * 16) = cvt8(v[2], v[3]);
  };
  auto loadB = [&](int c, bf16x8* br) {
#pragma unroll
    for (int ks = 0; ks < 4; ++ks) {
      const short* Bc = Bbase + (size_t)c * 4096 + ks * 1024;
      br[2 * ks]     = *(const bf16x8*)(Bc);
      br[2 * ks + 1] = *(const bf16x8*)(Bc + 256);
    }
  };
  auto compute = [&](int buf, const bf16x8* br) {
    const char* Ab = smem + buf * 8192;
#pragma unroll
    for (int ks = 0; ks < 4; ++ks) {
      const int kg   = 2 * ks + hh;
      const int slot = la ^ ((kg & 3) << 2);
      const int off  = kg * 1024 + slot * 16;
      bf16x8 a0 = *(const bf16x8*)(Ab + off);
      bf16x8 a1 = *(const bf16x8*)(Ab + off + 512);
      acc[0][0] = __builtin_amdgcn_mfma_f32_32x32x16_bf16(a0, br[2*ks],   acc[0][0], 0, 0, 0);
      acc[0][1] = __builtin_amdgcn_mfma_f32_32x32x16_bf16(a0, br[2*ks+1], acc[0][1], 0, 0, 0);
      acc[1][0] = __builtin_amdgcn_mfma_f32_32x32x16_bf16(a1, br[2*ks],   acc[1][0], 0, 0, 0);
      acc[1][1] = __builtin_amdgcn_mfma_f32_32x32x16_bf16(a1, br[2*ks+1], acc[1][1], 0, 0, 0);
    }
  };

  // ---- prologue ----
  ldA(0);
  wrA(0);                              // waits A(0) (prime)
  loadB(0, bregA);                     // B(0): issued after the A(0) wait
  ldA(1);                              // A(1) in flight across barrier
  BAR();

  // ---- K loop, unrolled x2 for static breg double-buffer ----
#pragma unroll
  for (int cc = 0; cc < NCHUNK; cc += 2) {
    // even iter c = cc: compute buf0 with B(cc)=bregA
    wrA(1);                            // A(cc+1) -> buf1
    loadB(cc + 1, bregB);              // B(cc+1): BEFORE the HBM prefetch
    if (cc + 2 < NCHUNK) ldA(cc + 2);  // A(cc+2) HBM, newest in FIFO
    compute(0, bregA);
    BAR();
    // odd iter c = cc+1: compute buf1 with B(cc+1)=bregB
    if (cc + 2 < NCHUNK) {
      wrA(0);                          // A(cc+2) -> buf0
      loadB(cc + 2, bregA);            // B(cc+2)
    }
    if (cc + 3 < NCHUNK) ldA(cc + 3);  // A(cc+3)
    compute(1, bregB);
    BAR();
  }

  // ---- epilogue: cprev loads first (overlap activation math) ----
  const int ccol = tid & 63;
  const int rg   = tid >> 6;
  const size_t gbase = (size_t)(m0 + rg * 16) * 256 + n0 + ccol;
  float cp[16];
#pragma unroll
  for (int j = 0; j < 16; ++j) cp[j] = cprev[gbase + (size_t)j * 256];

  // bias + activation -> transposed gate buffer [g][col][row]
  const float* bptr = (g == 0) ? bfp : (g == 1) ? bip : (g == 2) ? bcp : bop;
  const float bias0 = bptr[n0 + la];
  const float bias1 = bptr[n0 + 32 + la];
  short* G = (short*)smem;
#pragma unroll
  for (int mi = 0; mi < 2; ++mi)
#pragma unroll
    for (int ni = 0; ni < 2; ++ni) {
      const float bias = ni ? bias1 : bias0;
      const int   col  = la + ni * 32;
#pragma unroll
      for (int rq = 0; rq < 4; ++rq) {
        const int row0 = rq * 8 + 4 * hh + mi * 32;
        float t[4];
#pragma unroll
        for (int e = 0; e < 4; ++e) {
          float vv = acc[mi][ni][rq * 4 + e] + bias;
          t[e] = (g == 2) ? (1.f - 2.f / (__expf(2.f * vv) + 1.f))   // tanh
                          : (1.f / (1.f + __expf(-vv)));             // sigmoid
        }
        uint2 u; u.x = pk2(t[0], t[1]); u.y = pk2(t[2], t[3]);
        *(uint2*)(G + g * GSZ + col * ROWP + row0) = u;
      }
    }
  BAR();

  // ---- combine + store: thread -> col = tid&63, rows rg*16..+15 ----
  {
    const short* Gp = G + ccol * ROWP + rg * 16;
    bf16x8 gf[4][2];
#pragma unroll
    for (int gg = 0; gg < 4; ++gg) {
      gf[gg][0] = *(const bf16x8*)(Gp + gg * GSZ);
      gf[gg][1] = *(const bf16x8*)(Gp + gg * GSZ + 8);
    }
#pragma unroll
    for (int j = 0; j < 16; ++j) {
      float fg = bf2f(gf[0][j >> 3][j & 7]);
      float ig = bf2f(gf[1][j >> 3][j & 7]);
      float cg = bf2f(gf[2][j >> 3][j & 7]);
      float og = bf2f(gf[3][j >> 3][j & 7]);
      float cnew = fg * cp[j] + ig * cg;
      float hnew = og * (1.f - 2.f / (__expf(2.f * cnew) + 1.f));
      hout[gbase + (size_t)j * 256] = hnew;
      cout[gbase + (size_t)j * 256] = cnew;
    }
  }
}

extern "C" void kernel_launch(void* const* d_in, const int* in_sizes, int n_in,
                              void* d_out, int out_size, void* d_ws, size_t ws_size,
                              hipStream_t stream) {
  const float* x     = (const float*)d_in[0];
  const float* hprev = (const float*)d_in[1];
  const float* cprev = (const float*)d_in[2];
  const float* Wf    = (const float*)d_in[3];
  const float* Wi    = (const float*)d_in[4];
  const float* Wc    = (const float*)d_in[5];
  const float* Wo    = (const float*)d_in[6];
  const float* bfp   = (const float*)d_in[7];
  const float* bip   = (const float*)d_in[8];
  const float* bcp   = (const float*)d_in[9];
  const float* bop   = (const float*)d_in[10];
  float* out = (float*)d_out;
  short* Wt  = (short*)d_ws;     // 1 MB scratch

  cvt_weights<<<2048, 256, 0, stream>>>(Wf, Wi, Wc, Wo, Wt);

  lstm_fused<<<dim3(4096), dim3(256), SMEM_BYTES, stream>>>(
      x, hprev, cprev, Wt, bfp, bip, bcp, bop,
      out, out + (size_t)BATCH * UNITS);
}

// Round 6
// 151.726 us; speedup vs baseline: 2.2920x; 2.2920x over previous
//
#include <hip/hip_runtime.h>
#include <hip/hip_bf16.h>
#include <stdint.h>

#define BATCH   65536
#define UNITS   256
#define NCHUNK  8
#define ROWP    68                     // shorts per column in gate buffer (2-bank stride)
#define GSZ     (64 * ROWP)            // 4352 shorts per gate
#define SMEM_BYTES 34816               // max(A dbuf 16384, G 4*GSZ*2 = 34816)

using f32x16 = __attribute__((ext_vector_type(16))) float;
using bf16x8 = __attribute__((ext_vector_type(8))) short;

__device__ __forceinline__ short f2bf(float f) {
  union { float f; unsigned u; } v; v.f = f;
  unsigned r = v.u + 0x7FFFu + ((v.u >> 16) & 1u);   // RNE (prepass only)
  return (short)(r >> 16);
}
__device__ __forceinline__ float bf2f(short s) {
  union { float f; unsigned u; } v; v.u = ((unsigned)(unsigned short)s) << 16;
  return v.f;
}
__device__ __forceinline__ unsigned pk2(float a, float b) {   // v_cvt_pk_bf16_f32
  union { __hip_bfloat162 h; unsigned u; } cv;
  cv.h = __float22bfloat162_rn(make_float2(a, b));
  return cv.u;
}
__device__ __forceinline__ bf16x8 cvt8(float4 a, float4 b) {
  union { unsigned u[4]; bf16x8 v; } r;
  r.u[0] = pk2(a.x, a.y); r.u[1] = pk2(a.z, a.w);
  r.u[2] = pk2(b.x, b.y); r.u[3] = pk2(b.z, b.w);
  return r.v;
}

#define BAR() do { asm volatile("s_waitcnt lgkmcnt(0)" ::: "memory"); \
                   __builtin_amdgcn_s_barrier(); } while (0)

// ---- prepass: W_g fp32 [512][256] -> Wt bf16 tiled [g][nb][c][kg][n][k8]
__global__ void cvt_weights(const float* __restrict__ Wf, const float* __restrict__ Wi,
                            const float* __restrict__ Wc, const float* __restrict__ Wo,
                            short* __restrict__ Wt) {
  int idx = blockIdx.x * 256 + threadIdx.x;
  int g   = idx >> 17;
  int k   = (idx >> 8) & 511;
  int col = idx & 255;
  const float* W = (g == 0) ? Wf : (g == 1) ? Wi : (g == 2) ? Wc : Wo;
  float val = W[k * 256 + col];
  int nb = col >> 6, n = col & 63;
  int c = k >> 6, kg = (k >> 3) & 7, k8 = k & 7;
  int out = ((((g * 4 + nb) * 8 + c) * 8 + kg) * 64 + n) * 8 + k8;
  Wt[out] = f2bf(val);
}

// ---- fused LSTM cell: 4 waves/block, wave = gate; A LDS dbuf staged 3 ahead,
// B one chunk ahead in registers. FIFO-ordered VMEM: all L2 B loads issue
// BEFORE the iteration's HBM A prefetch (vmcnt completes in order — a B wait
// must never sit behind a younger-in-flight HBM load). Counted-wait barriers.
__global__ __launch_bounds__(256, 3) void lstm_fused(
    const float* __restrict__ x, const float* __restrict__ hprev,
    const float* __restrict__ cprev, const short* __restrict__ Wt,
    const float* __restrict__ bfp, const float* __restrict__ bip,
    const float* __restrict__ bcp, const float* __restrict__ bop,
    float* __restrict__ hout, float* __restrict__ cout)
{
  extern __shared__ __align__(16) char smem[];
  const int tid  = threadIdx.x;
  const int g    = tid >> 6;           // wave = gate
  const int lane = tid & 63;
  const int la   = lane & 31;
  const int hh   = lane >> 5;

  int bid = blockIdx.x;
  int wg  = (bid & 7) * 512 + (bid >> 3);      // XCD-bijective swizzle
  const int m0 = (wg >> 2) * 64;
  const int nb = wg & 3;
  const int n0 = nb * 64;

  const short* Bbase = Wt + ((size_t)(g * 4 + nb)) * 32768 + hh * 512 + la * 8;

  f32x16 acc[2][2] = {};
  bf16x8 breg[8];
  float4 vA[2][4];

  const int arow  = tid >> 2;
  const int q     = tid & 3;
  const int slotW = (arow ^ (q << 2)) & 63;

  auto ldA = [&](int c, float4* v) {
    const float* base = (c < 4) ? x : hprev;
    const float* rowp = base + (size_t)(m0 + arow) * 256 + (c & 3) * 64;
    v[0] = *(const float4*)(rowp + q * 8);
    v[1] = *(const float4*)(rowp + q * 8 + 4);
    v[2] = *(const float4*)(rowp + (q + 4) * 8);
    v[3] = *(const float4*)(rowp + (q + 4) * 8 + 4);
  };
  auto wrA = [&](int buf, const float4* v) {
    char* Ab = smem + buf * 8192;
    *(bf16x8*)(Ab + q * 1024 + slotW * 16)       = cvt8(v[0], v[1]);
    *(bf16x8*)(Ab + (q + 4) * 1024 + slotW * 16) = cvt8(v[2], v[3]);
  };
  auto loadB = [&](int c, int ks) {
    const short* Bc = Bbase + (size_t)c * 4096 + ks * 1024;
    breg[2 * ks]     = *(const bf16x8*)(Bc);
    breg[2 * ks + 1] = *(const bf16x8*)(Bc + 256);
  };

  // epilogue-combine indices (cprev loads issued early, before the K loop)
  const int ccol = tid & 63;
  const int rg   = tid >> 6;
  const size_t gbase = (size_t)(m0 + rg * 16) * 256 + n0 + ccol;

  // ---- prologue: FIFO order A0, A1, [wait A0] B0, cp, A2 ----
  ldA(0, vA[0]);                       // A(0) in flight
  ldA(1, vA[1]);                       // A(1) in flight
  wrA(0, vA[0]);                       // waits A(0) only (oldest)
#pragma unroll
  for (int ks = 0; ks < 4; ++ks) loadB(0, ks);   // B(0): after the A(0) wait
  float cp[16];
#pragma unroll
  for (int j = 0; j < 16; ++j) cp[j] = cprev[gbase + (size_t)j * 256];
  ldA(2, vA[0]);                       // A(2): newest in FIFO
  BAR();

  // ---- fully unrolled pipelined K loop (static vA indices — no scratch) ----
  int buf = 0;
#pragma unroll
  for (int c = 0; c < NCHUNK; ++c) {
    if (c + 1 < NCHUNK) wrA(buf ^ 1, vA[(c + 1) & 1]);  // A(c+1): ~2 iters old
    const char*  Ab = smem + buf * 8192;
    const short* Bn = Bbase + (size_t)((c + 1) & 7) * 4096;
    __builtin_amdgcn_s_setprio(1);
#pragma unroll
    for (int ks = 0; ks < 4; ++ks) {
      const int kg   = 2 * ks + hh;
      const int slot = la ^ ((kg & 3) << 2);
      const int off  = kg * 1024 + slot * 16;
      bf16x8 a0 = *(const bf16x8*)(Ab + off);
      bf16x8 a1 = *(const bf16x8*)(Ab + off + 512);
      acc[0][0] = __builtin_amdgcn_mfma_f32_32x32x16_bf16(a0, breg[2*ks],   acc[0][0], 0, 0, 0);
      acc[0][1] = __builtin_amdgcn_mfma_f32_32x32x16_bf16(a0, breg[2*ks+1], acc[0][1], 0, 0, 0);
      acc[1][0] = __builtin_amdgcn_mfma_f32_32x32x16_bf16(a1, breg[2*ks],   acc[1][0], 0, 0, 0);
      acc[1][1] = __builtin_amdgcn_mfma_f32_32x32x16_bf16(a1, breg[2*ks+1], acc[1][1], 0, 0, 0);
      breg[2*ks]     = *(const bf16x8*)(Bn + ks * 1024);        // prefetch c+1 (L2)
      breg[2*ks + 1] = *(const bf16x8*)(Bn + ks * 1024 + 256);
    }
    __builtin_amdgcn_s_setprio(0);
    __builtin_amdgcn_sched_barrier(0);             // pin: all B(c+1) before A HBM
    if (c + 3 < NCHUNK) ldA(c + 3, vA[(c + 3) & 1]);   // HBM prefetch, FIFO-newest
    __builtin_amdgcn_sched_barrier(0);
    BAR();                             // lgkmcnt(0)+s_barrier; vmcnt stays live
    buf ^= 1;
  }

  // ---- epilogue: bias+activation -> transposed gate buffer [g][col][row]
  const float* bptr = (g == 0) ? bfp : (g == 1) ? bip : (g == 2) ? bcp : bop;
  const float bias0 = bptr[n0 + la];
  const float bias1 = bptr[n0 + 32 + la];
  short* G = (short*)smem;
#pragma unroll
  for (int mi = 0; mi < 2; ++mi)
#pragma unroll
    for (int ni = 0; ni < 2; ++ni) {
      const float bias = ni ? bias1 : bias0;
      const int   col  = la + ni * 32;
#pragma unroll
      for (int rq = 0; rq < 4; ++rq) {
        const int row0 = rq * 8 + 4 * hh + mi * 32;
        float t[4];
#pragma unroll
        for (int e = 0; e < 4; ++e) {
          float vv = acc[mi][ni][rq * 4 + e] + bias;
          t[e] = (g == 2) ? (1.f - 2.f / (__expf(2.f * vv) + 1.f))   // tanh
                          : (1.f / (1.f + __expf(-vv)));             // sigmoid
        }
        uint2 u; u.x = pk2(t[0], t[1]); u.y = pk2(t[2], t[3]);
        *(uint2*)(G + g * GSZ + col * ROWP + row0) = u;
      }
    }
  BAR();

  // ---- combine + store: thread -> col = tid&63, rows rg*16..+15 ----
  {
    const short* Gp = G + ccol * ROWP + rg * 16;
    bf16x8 gf[4][2];
#pragma unroll
    for (int gg = 0; gg < 4; ++gg) {
      gf[gg][0] = *(const bf16x8*)(Gp + gg * GSZ);
      gf[gg][1] = *(const bf16x8*)(Gp + gg * GSZ + 8);
    }
#pragma unroll
    for (int j = 0; j < 16; ++j) {
      float fg = bf2f(gf[0][j >> 3][j & 7]);
      float ig = bf2f(gf[1][j >> 3][j & 7]);
      float cg = bf2f(gf[2][j >> 3][j & 7]);
      float og = bf2f(gf[3][j >> 3][j & 7]);
      float cnew = fg * cp[j] + ig * cg;
      float hnew = og * (1.f - 2.f / (__expf(2.f * cnew) + 1.f));
      hout[gbase + (size_t)j * 256] = hnew;
      cout[gbase + (size_t)j * 256] = cnew;
    }
  }
}

extern "C" void kernel_launch(void* const* d_in, const int* in_sizes, int n_in,
                              void* d_out, int out_size, void* d_ws, size_t ws_size,
                              hipStream_t stream) {
  const float* x     = (const float*)d_in[0];
  const float* hprev = (const float*)d_in[1];
  const float* cprev = (const float*)d_in[2];
  const float* Wf    = (const float*)d_in[3];
  const float* Wi    = (const float*)d_in[4];
  const float* Wc    = (const float*)d_in[5];
  const float* Wo    = (const float*)d_in[6];
  const float* bfp   = (const float*)d_in[7];
  const float* bip   = (const float*)d_in[8];
  const float* bcp   = (const float*)d_in[9];
  const float* bop   = (const float*)d_in[10];
  float* out = (float*)d_out;
  short* Wt  = (short*)d_ws;     // 1 MB scratch

  cvt_weights<<<2048, 256, 0, stream>>>(Wf, Wi, Wc, Wo, Wt);

  lstm_fused<<<dim3(4096), dim3(256), SMEM_BYTES, stream>>>(
      x, hprev, cprev, Wt, bfp, bip, bcp, bop,
      out, out + (size_t)BATCH * UNITS);
}

// Round 7
// 150.574 us; speedup vs baseline: 2.3095x; 1.0077x over previous
//
#include <hip/hip_runtime.h>
#include <hip/hip_bf16.h>
#include <stdint.h>

#define BATCH   65536
#define UNITS   256
#define NCHUNK  8
#define ROWP    68                     // shorts per column in gate buffer (2-bank stride)
#define GSZ     (64 * ROWP)            // 4352 shorts per gate
#define SMEM_BYTES 34816               // max(A dbuf 16384, G 4*GSZ*2 = 34816)

using f32x16 = __attribute__((ext_vector_type(16))) float;
using bf16x8 = __attribute__((ext_vector_type(8))) short;

__device__ __forceinline__ short f2bf(float f) {
  union { float f; unsigned u; } v; v.f = f;
  unsigned r = v.u + 0x7FFFu + ((v.u >> 16) & 1u);   // RNE (prepass only)
  return (short)(r >> 16);
}
__device__ __forceinline__ float bf2f(short s) {
  union { float f; unsigned u; } v; v.u = ((unsigned)(unsigned short)s) << 16;
  return v.f;
}
__device__ __forceinline__ unsigned pk2(float a, float b) {   // v_cvt_pk_bf16_f32
  union { __hip_bfloat162 h; unsigned u; } cv;
  cv.h = __float22bfloat162_rn(make_float2(a, b));
  return cv.u;
}
__device__ __forceinline__ bf16x8 cvt8(float4 a, float4 b) {
  union { unsigned u[4]; bf16x8 v; } r;
  r.u[0] = pk2(a.x, a.y); r.u[1] = pk2(a.z, a.w);
  r.u[2] = pk2(b.x, b.y); r.u[3] = pk2(b.z, b.w);
  return r.v;
}

#define BAR() do { asm volatile("s_waitcnt lgkmcnt(0)" ::: "memory"); \
                   __builtin_amdgcn_s_barrier(); } while (0)

// ---- prepass: W_g fp32 [512][256] -> Wt bf16 tiled [g][nb][c][kg][n][k8]
__global__ void cvt_weights(const float* __restrict__ Wf, const float* __restrict__ Wi,
                            const float* __restrict__ Wc, const float* __restrict__ Wo,
                            short* __restrict__ Wt) {
  int idx = blockIdx.x * 256 + threadIdx.x;
  int g   = idx >> 17;
  int k   = (idx >> 8) & 511;
  int col = idx & 255;
  const float* W = (g == 0) ? Wf : (g == 1) ? Wi : (g == 2) ? Wc : Wo;
  float val = W[k * 256 + col];
  int nb = col >> 6, n = col & 63;
  int c = k >> 6, kg = (k >> 3) & 7, k8 = k & 7;
  int out = ((((g * 4 + nb) * 8 + c) * 8 + kg) * 64 + n) * 8 + k8;
  Wt[out] = f2bf(val);
}

// ---- fused LSTM cell: 4 waves/block, wave = gate; A LDS dbuf staged 3 ahead,
// B one chunk ahead in registers. FIFO-ordered VMEM: all L2 B loads issue
// BEFORE the iteration's HBM A prefetch (vmcnt completes in order — a B wait
// must never sit behind a younger-in-flight HBM load). Counted-wait barriers.
__global__ __launch_bounds__(256, 3) void lstm_fused(
    const float* __restrict__ x, const float* __restrict__ hprev,
    const float* __restrict__ cprev, const short* __restrict__ Wt,
    const float* __restrict__ bfp, const float* __restrict__ bip,
    const float* __restrict__ bcp, const float* __restrict__ bop,
    float* __restrict__ hout, float* __restrict__ cout)
{
  extern __shared__ __align__(16) char smem[];
  const int tid  = threadIdx.x;
  const int g    = tid >> 6;           // wave = gate
  const int lane = tid & 63;
  const int la   = lane & 31;
  const int hh   = lane >> 5;

  int bid = blockIdx.x;
  int wg  = (bid & 7) * 512 + (bid >> 3);      // XCD-bijective swizzle
  const int m0 = (wg >> 2) * 64;
  const int nb = wg & 3;
  const int n0 = nb * 64;

  const short* Bbase = Wt + ((size_t)(g * 4 + nb)) * 32768 + hh * 512 + la * 8;

  f32x16 acc[2][2] = {};
  bf16x8 breg[8];
  float4 vA[2][4];

  const int arow  = tid >> 2;
  const int q     = tid & 3;
  const int slotW = (arow ^ (q << 2)) & 63;

  auto ldA = [&](int c, float4* v) {
    const float* base = (c < 4) ? x : hprev;
    const float* rowp = base + (size_t)(m0 + arow) * 256 + (c & 3) * 64;
    v[0] = *(const float4*)(rowp + q * 8);
    v[1] = *(const float4*)(rowp + q * 8 + 4);
    v[2] = *(const float4*)(rowp + (q + 4) * 8);
    v[3] = *(const float4*)(rowp + (q + 4) * 8 + 4);
  };
  auto wrA = [&](int buf, const float4* v) {
    char* Ab = smem + buf * 8192;
    *(bf16x8*)(Ab + q * 1024 + slotW * 16)       = cvt8(v[0], v[1]);
    *(bf16x8*)(Ab + (q + 4) * 1024 + slotW * 16) = cvt8(v[2], v[3]);
  };
  auto loadB = [&](int c, int ks) {
    const short* Bc = Bbase + (size_t)c * 4096 + ks * 1024;
    breg[2 * ks]     = *(const bf16x8*)(Bc);
    breg[2 * ks + 1] = *(const bf16x8*)(Bc + 256);
  };

  // epilogue-combine indices (cprev loads issued early, before the K loop)
  const int ccol = tid & 63;
  const int rg   = tid >> 6;
  const size_t gbase = (size_t)(m0 + rg * 16) * 256 + n0 + ccol;

  // ---- prologue: FIFO order A0, A1, [wait A0] B0, cp, A2 ----
  ldA(0, vA[0]);                       // A(0) in flight
  ldA(1, vA[1]);                       // A(1) in flight
  wrA(0, vA[0]);                       // waits A(0) only (oldest)
#pragma unroll
  for (int ks = 0; ks < 4; ++ks) loadB(0, ks);   // B(0): after the A(0) wait
  float cp[16];
#pragma unroll
  for (int j = 0; j < 16; ++j) cp[j] = cprev[gbase + (size_t)j * 256];
  ldA(2, vA[0]);                       // A(2): newest in FIFO
  BAR();

  // ---- fully unrolled pipelined K loop (static vA indices — no scratch) ----
  int buf = 0;
#pragma unroll
  for (int c = 0; c < NCHUNK; ++c) {
    if (c + 1 < NCHUNK) wrA(buf ^ 1, vA[(c + 1) & 1]);  // A(c+1): ~2 iters old
    const char*  Ab = smem + buf * 8192;
    const short* Bn = Bbase + (size_t)((c + 1) & 7) * 4096;
    __builtin_amdgcn_s_setprio(1);
#pragma unroll
    for (int ks = 0; ks < 4; ++ks) {
      const int kg   = 2 * ks + hh;
      const int slot = la ^ ((kg & 3) << 2);
      const int off  = kg * 1024 + slot * 16;
      bf16x8 a0 = *(const bf16x8*)(Ab + off);
      bf16x8 a1 = *(const bf16x8*)(Ab + off + 512);
      acc[0][0] = __builtin_amdgcn_mfma_f32_32x32x16_bf16(a0, breg[2*ks],   acc[0][0], 0, 0, 0);
      acc[0][1] = __builtin_amdgcn_mfma_f32_32x32x16_bf16(a0, breg[2*ks+1], acc[0][1], 0, 0, 0);
      acc[1][0] = __builtin_amdgcn_mfma_f32_32x32x16_bf16(a1, breg[2*ks],   acc[1][0], 0, 0, 0);
      acc[1][1] = __builtin_amdgcn_mfma_f32_32x32x16_bf16(a1, breg[2*ks+1], acc[1][1], 0, 0, 0);
      breg[2*ks]     = *(const bf16x8*)(Bn + ks * 1024);        // prefetch c+1 (L2)
      breg[2*ks + 1] = *(const bf16x8*)(Bn + ks * 1024 + 256);
    }
    __builtin_amdgcn_s_setprio(0);
    __builtin_amdgcn_sched_barrier(0);             // pin: all B(c+1) before A HBM
    if (c + 3 < NCHUNK) ldA(c + 3, vA[(c + 3) & 1]);   // HBM prefetch, FIFO-newest
    __builtin_amdgcn_sched_barrier(0);
    BAR();                             // lgkmcnt(0)+s_barrier; vmcnt stays live
    buf ^= 1;
  }

  // ---- epilogue: bias+activation -> transposed gate buffer [g][col][row]
  const float* bptr = (g == 0) ? bfp : (g == 1) ? bip : (g == 2) ? bcp : bop;
  const float bias0 = bptr[n0 + la];
  const float bias1 = bptr[n0 + 32 + la];
  short* G = (short*)smem;
#pragma unroll
  for (int mi = 0; mi < 2; ++mi)
#pragma unroll
    for (int ni = 0; ni < 2; ++ni) {
      const float bias = ni ? bias1 : bias0;
      const int   col  = la + ni * 32;
#pragma unroll
      for (int rq = 0; rq < 4; ++rq) {
        const int row0 = rq * 8 + 4 * hh + mi * 32;
        float t[4];
#pragma unroll
        for (int e = 0; e < 4; ++e) {
          float vv = acc[mi][ni][rq * 4 + e] + bias;
          t[e] = (g == 2) ? (1.f - 2.f / (__expf(2.f * vv) + 1.f))   // tanh
                          : (1.f / (1.f + __expf(-vv)));             // sigmoid
        }
        uint2 u; u.x = pk2(t[0], t[1]); u.y = pk2(t[2], t[3]);
        *(uint2*)(G + g * GSZ + col * ROWP + row0) = u;
      }
    }
  BAR();

  // ---- combine + store: thread -> col = tid&63, rows rg*16..+15 ----
  {
    const short* Gp = G + ccol * ROWP + rg * 16;
    bf16x8 gf[4][2];
#pragma unroll
    for (int gg = 0; gg < 4; ++gg) {
      gf[gg][0] = *(const bf16x8*)(Gp + gg * GSZ);
      gf[gg][1] = *(const bf16x8*)(Gp + gg * GSZ + 8);
    }
#pragma unroll
    for (int j = 0; j < 16; ++j) {
      float fg = bf2f(gf[0][j >> 3][j & 7]);
      float ig = bf2f(gf[1][j >> 3][j & 7]);
      float cg = bf2f(gf[2][j >> 3][j & 7]);
      float og = bf2f(gf[3][j >> 3][j & 7]);
      float cnew = fg * cp[j] + ig * cg;
      float hnew = og * (1.f - 2.f / (__expf(2.f * cnew) + 1.f));
      hout[gbase + (size_t)j * 256] = hnew;
      cout[gbase + (size_t)j * 256] = cnew;
    }
  }
}

extern "C" void kernel_launch(void* const* d_in, const int* in_sizes, int n_in,
                              void* d_out, int out_size, void* d_ws, size_t ws_size,
                              hipStream_t stream) {
  const float* x     = (const float*)d_in[0];
  const float* hprev = (const float*)d_in[1];
  const float* cprev = (const float*)d_in[2];
  const float* Wf    = (const float*)d_in[3];
  const float* Wi    = (const float*)d_in[4];
  const float* Wc    = (const float*)d_in[5];
  const float* Wo    = (const float*)d_in[6];
  const float* bfp   = (const float*)d_in[7];
  const float* bip   = (const float*)d_in[8];
  const float* bcp   = (const float*)d_in[9];
  const float* bop   = (const float*)d_in[10];
  float* out = (float*)d_out;
  short* Wt  = (short*)d_ws;     // 1 MB scratch

  cvt_weights<<<2048, 256, 0, stream>>>(Wf, Wi, Wc, Wo, Wt);

  lstm_fused<<<dim3(4096), dim3(256), SMEM_BYTES, stream>>>(
      x, hprev, cprev, Wt, bfp, bip, bcp, bop,
      out, out + (size_t)BATCH * UNITS);
}

// Round 8
// 150.551 us; speedup vs baseline: 2.3099x; 1.0002x over previous
//
#include <hip/hip_runtime.h>
#include <hip/hip_bf16.h>
#include <stdint.h>

#define BATCH   65536
#define UNITS   256
#define NCHUNK  8
#define ROWP    68                     // shorts per column in gate buffer (2-bank stride)
#define GSZ     (64 * ROWP)            // 4352 shorts per gate
#define SMEM_BYTES 34816               // max(A dbuf 16384, G 4*GSZ*2 = 34816)

using f32x16 = __attribute__((ext_vector_type(16))) float;
using bf16x8 = __attribute__((ext_vector_type(8))) short;

__device__ __forceinline__ short f2bf(float f) {
  union { float f; unsigned u; } v; v.f = f;
  unsigned r = v.u + 0x7FFFu + ((v.u >> 16) & 1u);   // RNE (prepass only)
  return (short)(r >> 16);
}
__device__ __forceinline__ float bf2f(short s) {
  union { float f; unsigned u; } v; v.u = ((unsigned)(unsigned short)s) << 16;
  return v.f;
}
__device__ __forceinline__ unsigned pk2(float a, float b) {   // v_cvt_pk_bf16_f32
  union { __hip_bfloat162 h; unsigned u; } cv;
  cv.h = __float22bfloat162_rn(make_float2(a, b));
  return cv.u;
}
__device__ __forceinline__ bf16x8 cvt8(float4 a, float4 b) {
  union { unsigned u[4]; bf16x8 v; } r;
  r.u[0] = pk2(a.x, a.y); r.u[1] = pk2(a.z, a.w);
  r.u[2] = pk2(b.x, b.y); r.u[3] = pk2(b.z, b.w);
  return r.v;
}

#define BAR() do { asm volatile("s_waitcnt lgkmcnt(0)" ::: "memory"); \
                   __builtin_amdgcn_s_barrier(); } while (0)

// ---- prepass: W_g fp32 [512][256] -> Wt bf16 tiled [g][nb][c][kg][n][k8]
__global__ void cvt_weights(const float* __restrict__ Wf, const float* __restrict__ Wi,
                            const float* __restrict__ Wc, const float* __restrict__ Wo,
                            short* __restrict__ Wt) {
  int idx = blockIdx.x * 256 + threadIdx.x;
  int g   = idx >> 17;
  int k   = (idx >> 8) & 511;
  int col = idx & 255;
  const float* W = (g == 0) ? Wf : (g == 1) ? Wi : (g == 2) ? Wc : Wo;
  float val = W[k * 256 + col];
  int nb = col >> 6, n = col & 63;
  int c = k >> 6, kg = (k >> 3) & 7, k8 = k & 7;
  int out = ((((g * 4 + nb) * 8 + c) * 8 + kg) * 64 + n) * 8 + k8;
  Wt[out] = f2bf(val);
}

// ---- fused LSTM cell: 4 waves/block, wave = gate; A LDS dbuf staged 3 ahead,
// B one chunk ahead in registers. FIFO-ordered VMEM: all L2 B loads issue
// BEFORE the iteration's HBM A prefetch (vmcnt completes in order — a B wait
// must never sit behind a younger-in-flight HBM load). Counted-wait barriers.
__global__ __launch_bounds__(256, 3) void lstm_fused(
    const float* __restrict__ x, const float* __restrict__ hprev,
    const float* __restrict__ cprev, const short* __restrict__ Wt,
    const float* __restrict__ bfp, const float* __restrict__ bip,
    const float* __restrict__ bcp, const float* __restrict__ bop,
    float* __restrict__ hout, float* __restrict__ cout)
{
  extern __shared__ __align__(16) char smem[];
  const int tid  = threadIdx.x;
  const int g    = tid >> 6;           // wave = gate
  const int lane = tid & 63;
  const int la   = lane & 31;
  const int hh   = lane >> 5;

  int bid = blockIdx.x;
  int wg  = (bid & 7) * 512 + (bid >> 3);      // XCD-bijective swizzle
  const int m0 = (wg >> 2) * 64;
  const int nb = wg & 3;
  const int n0 = nb * 64;

  const short* Bbase = Wt + ((size_t)(g * 4 + nb)) * 32768 + hh * 512 + la * 8;

  f32x16 acc[2][2] = {};
  bf16x8 breg[8];
  float4 vA[2][4];

  const int arow  = tid >> 2;
  const int q     = tid & 3;
  const int slotW = (arow ^ (q << 2)) & 63;

  auto ldA = [&](int c, float4* v) {
    const float* base = (c < 4) ? x : hprev;
    const float* rowp = base + (size_t)(m0 + arow) * 256 + (c & 3) * 64;
    v[0] = *(const float4*)(rowp + q * 8);
    v[1] = *(const float4*)(rowp + q * 8 + 4);
    v[2] = *(const float4*)(rowp + (q + 4) * 8);
    v[3] = *(const float4*)(rowp + (q + 4) * 8 + 4);
  };
  auto wrA = [&](int buf, const float4* v) {
    char* Ab = smem + buf * 8192;
    *(bf16x8*)(Ab + q * 1024 + slotW * 16)       = cvt8(v[0], v[1]);
    *(bf16x8*)(Ab + (q + 4) * 1024 + slotW * 16) = cvt8(v[2], v[3]);
  };
  auto loadB = [&](int c, int ks) {
    const short* Bc = Bbase + (size_t)c * 4096 + ks * 1024;
    breg[2 * ks]     = *(const bf16x8*)(Bc);
    breg[2 * ks + 1] = *(const bf16x8*)(Bc + 256);
  };

  // epilogue-combine indices (cprev loads issued early, before the K loop)
  const int ccol = tid & 63;
  const int rg   = tid >> 6;
  const size_t gbase = (size_t)(m0 + rg * 16) * 256 + n0 + ccol;

  // ---- prologue: FIFO order A0, A1, [wait A0] B0, cp, A2 ----
  ldA(0, vA[0]);                       // A(0) in flight
  ldA(1, vA[1]);                       // A(1) in flight
  wrA(0, vA[0]);                       // waits A(0) only (oldest)
#pragma unroll
  for (int ks = 0; ks < 4; ++ks) loadB(0, ks);   // B(0): after the A(0) wait
  float cp[16];
#pragma unroll
  for (int j = 0; j < 16; ++j) cp[j] = cprev[gbase + (size_t)j * 256];
  ldA(2, vA[0]);                       // A(2): newest in FIFO
  BAR();

  // ---- fully unrolled pipelined K loop (static vA indices — no scratch) ----
  int buf = 0;
#pragma unroll
  for (int c = 0; c < NCHUNK; ++c) {
    if (c + 1 < NCHUNK) wrA(buf ^ 1, vA[(c + 1) & 1]);  // A(c+1): ~2 iters old
    const char*  Ab = smem + buf * 8192;
    const short* Bn = Bbase + (size_t)((c + 1) & 7) * 4096;
    __builtin_amdgcn_s_setprio(1);
#pragma unroll
    for (int ks = 0; ks < 4; ++ks) {
      const int kg   = 2 * ks + hh;
      const int slot = la ^ ((kg & 3) << 2);
      const int off  = kg * 1024 + slot * 16;
      bf16x8 a0 = *(const bf16x8*)(Ab + off);
      bf16x8 a1 = *(const bf16x8*)(Ab + off + 512);
      acc[0][0] = __builtin_amdgcn_mfma_f32_32x32x16_bf16(a0, breg[2*ks],   acc[0][0], 0, 0, 0);
      acc[0][1] = __builtin_amdgcn_mfma_f32_32x32x16_bf16(a0, breg[2*ks+1], acc[0][1], 0, 0, 0);
      acc[1][0] = __builtin_amdgcn_mfma_f32_32x32x16_bf16(a1, breg[2*ks],   acc[1][0], 0, 0, 0);
      acc[1][1] = __builtin_amdgcn_mfma_f32_32x32x16_bf16(a1, breg[2*ks+1], acc[1][1], 0, 0, 0);
      breg[2*ks]     = *(const bf16x8*)(Bn + ks * 1024);        // prefetch c+1 (L2)
      breg[2*ks + 1] = *(const bf16x8*)(Bn + ks * 1024 + 256);
    }
    __builtin_amdgcn_s_setprio(0);
    __builtin_amdgcn_sched_barrier(0);             // pin: all B(c+1) before A HBM
    if (c + 3 < NCHUNK) ldA(c + 3, vA[(c + 3) & 1]);   // HBM prefetch, FIFO-newest
    __builtin_amdgcn_sched_barrier(0);
    BAR();                             // lgkmcnt(0)+s_barrier; vmcnt stays live
    buf ^= 1;
  }

  // ---- epilogue: bias+activation -> transposed gate buffer [g][col][row]
  const float* bptr = (g == 0) ? bfp : (g == 1) ? bip : (g == 2) ? bcp : bop;
  const float bias0 = bptr[n0 + la];
  const float bias1 = bptr[n0 + 32 + la];
  short* G = (short*)smem;
#pragma unroll
  for (int mi = 0; mi < 2; ++mi)
#pragma unroll
    for (int ni = 0; ni < 2; ++ni) {
      const float bias = ni ? bias1 : bias0;
      const int   col  = la + ni * 32;
#pragma unroll
      for (int rq = 0; rq < 4; ++rq) {
        const int row0 = rq * 8 + 4 * hh + mi * 32;
        float t[4];
#pragma unroll
        for (int e = 0; e < 4; ++e) {
          float vv = acc[mi][ni][rq * 4 + e] + bias;
          t[e] = (g == 2) ? (1.f - 2.f / (__expf(2.f * vv) + 1.f))   // tanh
                          : (1.f / (1.f + __expf(-vv)));             // sigmoid
        }
        uint2 u; u.x = pk2(t[0], t[1]); u.y = pk2(t[2], t[3]);
        *(uint2*)(G + g * GSZ + col * ROWP + row0) = u;
      }
    }
  BAR();

  // ---- combine + store: thread -> col = tid&63, rows rg*16..+15 ----
  {
    const short* Gp = G + ccol * ROWP + rg * 16;
    bf16x8 gf[4][2];
#pragma unroll
    for (int gg = 0; gg < 4; ++gg) {
      gf[gg][0] = *(const bf16x8*)(Gp + gg * GSZ);
      gf[gg][1] = *(const bf16x8*)(Gp + gg * GSZ + 8);
    }
#pragma unroll
    for (int j = 0; j < 16; ++j) {
      float fg = bf2f(gf[0][j >> 3][j & 7]);
      float ig = bf2f(gf[1][j >> 3][j & 7]);
      float cg = bf2f(gf[2][j >> 3][j & 7]);
      float og = bf2f(gf[3][j >> 3][j & 7]);
      float cnew = fg * cp[j] + ig * cg;
      float hnew = og * (1.f - 2.f / (__expf(2.f * cnew) + 1.f));
      hout[gbase + (size_t)j * 256] = hnew;
      cout[gbase + (size_t)j * 256] = cnew;
    }
  }
}

extern "C" void kernel_launch(void* const* d_in, const int* in_sizes, int n_in,
                              void* d_out, int out_size, void* d_ws, size_t ws_size,
                              hipStream_t stream) {
  const float* x     = (const float*)d_in[0];
  const float* hprev = (const float*)d_in[1];
  const float* cprev = (const float*)d_in[2];
  const float* Wf    = (const float*)d_in[3];
  const float* Wi    = (const float*)d_in[4];
  const float* Wc    = (const float*)d_in[5];
  const float* Wo    = (const float*)d_in[6];
  const float* bfp   = (const float*)d_in[7];
  const float* bip   = (const float*)d_in[8];
  const float* bcp   = (const float*)d_in[9];
  const float* bop   = (const float*)d_in[10];
  float* out = (float*)d_out;
  short* Wt  = (short*)d_ws;     // 1 MB scratch

  cvt_weights<<<2048, 256, 0, stream>>>(Wf, Wi, Wc, Wo, Wt);

  lstm_fused<<<dim3(4096), dim3(256), SMEM_BYTES, stream>>>(
      x, hprev, cprev, Wt, bfp, bip, bcp, bop,
      out, out + (size_t)BATCH * UNITS);
}

// Round 9
// 150.491 us; speedup vs baseline: 2.3108x; 1.0004x over previous
//
#include <hip/hip_runtime.h>
#include <hip/hip_bf16.h>
#include <stdint.h>

#define BATCH   65536
#define UNITS   256
#define NCHUNK  8
#define ROWP    68                     // shorts per column in gate buffer (2-bank stride)
#define GSZ     (64 * ROWP)            // 4352 shorts per gate
#define SMEM_BYTES 34816               // max(A dbuf 16384, G 4*GSZ*2 = 34816)

using f32x16 = __attribute__((ext_vector_type(16))) float;
using bf16x8 = __attribute__((ext_vector_type(8))) short;

__device__ __forceinline__ short f2bf(float f) {
  union { float f; unsigned u; } v; v.f = f;
  unsigned r = v.u + 0x7FFFu + ((v.u >> 16) & 1u);   // RNE (prepass only)
  return (short)(r >> 16);
}
__device__ __forceinline__ float bf2f(short s) {
  union { float f; unsigned u; } v; v.u = ((unsigned)(unsigned short)s) << 16;
  return v.f;
}
__device__ __forceinline__ unsigned pk2(float a, float b) {   // v_cvt_pk_bf16_f32
  union { __hip_bfloat162 h; unsigned u; } cv;
  cv.h = __float22bfloat162_rn(make_float2(a, b));
  return cv.u;
}
__device__ __forceinline__ bf16x8 cvt8(float4 a, float4 b) {
  union { unsigned u[4]; bf16x8 v; } r;
  r.u[0] = pk2(a.x, a.y); r.u[1] = pk2(a.z, a.w);
  r.u[2] = pk2(b.x, b.y); r.u[3] = pk2(b.z, b.w);
  return r.v;
}

#define BAR() do { asm volatile("s_waitcnt lgkmcnt(0)" ::: "memory"); \
                   __builtin_amdgcn_s_barrier(); } while (0)

// ---- prepass: W_g fp32 [512][256] -> Wt bf16 tiled [g][nb][c][kg][n][k8]
__global__ void cvt_weights(const float* __restrict__ Wf, const float* __restrict__ Wi,
                            const float* __restrict__ Wc, const float* __restrict__ Wo,
                            short* __restrict__ Wt) {
  int idx = blockIdx.x * 256 + threadIdx.x;
  int g   = idx >> 17;
  int k   = (idx >> 8) & 511;
  int col = idx & 255;
  const float* W = (g == 0) ? Wf : (g == 1) ? Wi : (g == 2) ? Wc : Wo;
  float val = W[k * 256 + col];
  int nb = col >> 6, n = col & 63;
  int c = k >> 6, kg = (k >> 3) & 7, k8 = k & 7;
  int out = ((((g * 4 + nb) * 8 + c) * 8 + kg) * 64 + n) * 8 + k8;
  Wt[out] = f2bf(val);
}

// ---- fused LSTM cell: 4 waves/block, wave = gate; A LDS dbuf staged 3 ahead,
// B one chunk ahead in registers. FIFO-ordered VMEM: all L2 B loads issue
// BEFORE the iteration's HBM A prefetch (vmcnt completes in order — a B wait
// must never sit behind a younger-in-flight HBM load). Counted-wait barriers.
__global__ __launch_bounds__(256, 3) void lstm_fused(
    const float* __restrict__ x, const float* __restrict__ hprev,
    const float* __restrict__ cprev, const short* __restrict__ Wt,
    const float* __restrict__ bfp, const float* __restrict__ bip,
    const float* __restrict__ bcp, const float* __restrict__ bop,
    float* __restrict__ hout, float* __restrict__ cout)
{
  extern __shared__ __align__(16) char smem[];
  const int tid  = threadIdx.x;
  const int g    = tid >> 6;           // wave = gate
  const int lane = tid & 63;
  const int la   = lane & 31;
  const int hh   = lane >> 5;

  int bid = blockIdx.x;
  int wg  = (bid & 7) * 512 + (bid >> 3);      // XCD-bijective swizzle
  const int m0 = (wg >> 2) * 64;
  const int nb = wg & 3;
  const int n0 = nb * 64;

  const short* Bbase = Wt + ((size_t)(g * 4 + nb)) * 32768 + hh * 512 + la * 8;

  f32x16 acc[2][2] = {};
  bf16x8 breg[8];
  float4 vA[2][4];

  const int arow  = tid >> 2;
  const int q     = tid & 3;
  const int slotW = (arow ^ (q << 2)) & 63;

  auto ldA = [&](int c, float4* v) {
    const float* base = (c < 4) ? x : hprev;
    const float* rowp = base + (size_t)(m0 + arow) * 256 + (c & 3) * 64;
    v[0] = *(const float4*)(rowp + q * 8);
    v[1] = *(const float4*)(rowp + q * 8 + 4);
    v[2] = *(const float4*)(rowp + (q + 4) * 8);
    v[3] = *(const float4*)(rowp + (q + 4) * 8 + 4);
  };
  auto wrA = [&](int buf, const float4* v) {
    char* Ab = smem + buf * 8192;
    *(bf16x8*)(Ab + q * 1024 + slotW * 16)       = cvt8(v[0], v[1]);
    *(bf16x8*)(Ab + (q + 4) * 1024 + slotW * 16) = cvt8(v[2], v[3]);
  };
  auto loadB = [&](int c, int ks) {
    const short* Bc = Bbase + (size_t)c * 4096 + ks * 1024;
    breg[2 * ks]     = *(const bf16x8*)(Bc);
    breg[2 * ks + 1] = *(const bf16x8*)(Bc + 256);
  };

  // epilogue-combine indices (cprev loads issued early, before the K loop)
  const int ccol = tid & 63;
  const int rg   = tid >> 6;
  const size_t gbase = (size_t)(m0 + rg * 16) * 256 + n0 + ccol;

  // ---- prologue: FIFO order A0, A1, [wait A0] B0, cp, A2 ----
  ldA(0, vA[0]);                       // A(0) in flight
  ldA(1, vA[1]);                       // A(1) in flight
  wrA(0, vA[0]);                       // waits A(0) only (oldest)
#pragma unroll
  for (int ks = 0; ks < 4; ++ks) loadB(0, ks);   // B(0): after the A(0) wait
  float cp[16];
#pragma unroll
  for (int j = 0; j < 16; ++j) cp[j] = cprev[gbase + (size_t)j * 256];
  ldA(2, vA[0]);                       // A(2): newest in FIFO
  BAR();

  // ---- fully unrolled pipelined K loop (static vA indices — no scratch) ----
  int buf = 0;
#pragma unroll
  for (int c = 0; c < NCHUNK; ++c) {
    if (c + 1 < NCHUNK) wrA(buf ^ 1, vA[(c + 1) & 1]);  // A(c+1): ~2 iters old
    const char*  Ab = smem + buf * 8192;
    const short* Bn = Bbase + (size_t)((c + 1) & 7) * 4096;
    __builtin_amdgcn_s_setprio(1);
#pragma unroll
    for (int ks = 0; ks < 4; ++ks) {
      const int kg   = 2 * ks + hh;
      const int slot = la ^ ((kg & 3) << 2);
      const int off  = kg * 1024 + slot * 16;
      bf16x8 a0 = *(const bf16x8*)(Ab + off);
      bf16x8 a1 = *(const bf16x8*)(Ab + off + 512);
      acc[0][0] = __builtin_amdgcn_mfma_f32_32x32x16_bf16(a0, breg[2*ks],   acc[0][0], 0, 0, 0);
      acc[0][1] = __builtin_amdgcn_mfma_f32_32x32x16_bf16(a0, breg[2*ks+1], acc[0][1], 0, 0, 0);
      acc[1][0] = __builtin_amdgcn_mfma_f32_32x32x16_bf16(a1, breg[2*ks],   acc[1][0], 0, 0, 0);
      acc[1][1] = __builtin_amdgcn_mfma_f32_32x32x16_bf16(a1, breg[2*ks+1], acc[1][1], 0, 0, 0);
      breg[2*ks]     = *(const bf16x8*)(Bn + ks * 1024);        // prefetch c+1 (L2)
      breg[2*ks + 1] = *(const bf16x8*)(Bn + ks * 1024 + 256);
    }
    __builtin_amdgcn_s_setprio(0);
    __builtin_amdgcn_sched_barrier(0);             // pin: all B(c+1) before A HBM
    if (c + 3 < NCHUNK) ldA(c + 3, vA[(c + 3) & 1]);   // HBM prefetch, FIFO-newest
    __builtin_amdgcn_sched_barrier(0);
    BAR();                             // lgkmcnt(0)+s_barrier; vmcnt stays live
    buf ^= 1;
  }

  // ---- epilogue: bias+activation -> transposed gate buffer [g][col][row]
  const float* bptr = (g == 0) ? bfp : (g == 1) ? bip : (g == 2) ? bcp : bop;
  const float bias0 = bptr[n0 + la];
  const float bias1 = bptr[n0 + 32 + la];
  short* G = (short*)smem;
#pragma unroll
  for (int mi = 0; mi < 2; ++mi)
#pragma unroll
    for (int ni = 0; ni < 2; ++ni) {
      const float bias = ni ? bias1 : bias0;
      const int   col  = la + ni * 32;
#pragma unroll
      for (int rq = 0; rq < 4; ++rq) {
        const int row0 = rq * 8 + 4 * hh + mi * 32;
        float t[4];
#pragma unroll
        for (int e = 0; e < 4; ++e) {
          float vv = acc[mi][ni][rq * 4 + e] + bias;
          t[e] = (g == 2) ? (1.f - 2.f / (__expf(2.f * vv) + 1.f))   // tanh
                          : (1.f / (1.f + __expf(-vv)));             // sigmoid
        }
        uint2 u; u.x = pk2(t[0], t[1]); u.y = pk2(t[2], t[3]);
        *(uint2*)(G + g * GSZ + col * ROWP + row0) = u;
      }
    }
  BAR();

  // ---- combine + store: thread -> col = tid&63, rows rg*16..+15 ----
  {
    const short* Gp = G + ccol * ROWP + rg * 16;
    bf16x8 gf[4][2];
#pragma unroll
    for (int gg = 0; gg < 4; ++gg) {
      gf[gg][0] = *(const bf16x8*)(Gp + gg * GSZ);
      gf[gg][1] = *(const bf16x8*)(Gp + gg * GSZ + 8);
    }
#pragma unroll
    for (int j = 0; j < 16; ++j) {
      float fg = bf2f(gf[0][j >> 3][j & 7]);
      float ig = bf2f(gf[1][j >> 3][j & 7]);
      float cg = bf2f(gf[2][j >> 3][j & 7]);
      float og = bf2f(gf[3][j >> 3][j & 7]);
      float cnew = fg * cp[j] + ig * cg;
      float hnew = og * (1.f - 2.f / (__expf(2.f * cnew) + 1.f));
      hout[gbase + (size_t)j * 256] = hnew;
      cout[gbase + (size_t)j * 256] = cnew;
    }
  }
}

extern "C" void kernel_launch(void* const* d_in, const int* in_sizes, int n_in,
                              void* d_out, int out_size, void* d_ws, size_t ws_size,
                              hipStream_t stream) {
  const float* x     = (const float*)d_in[0];
  const float* hprev = (const float*)d_in[1];
  const float* cprev = (const float*)d_in[2];
  const float* Wf    = (const float*)d_in[3];
  const float* Wi    = (const float*)d_in[4];
  const float* Wc    = (const float*)d_in[5];
  const float* Wo    = (const float*)d_in[6];
  const float* bfp   = (const float*)d_in[7];
  const float* bip   = (const float*)d_in[8];
  const float* bcp   = (const float*)d_in[9];
  const float* bop   = (const float*)d_in[10];
  float* out = (float*)d_out;
  short* Wt  = (short*)d_ws;     // 1 MB scratch

  cvt_weights<<<2048, 256, 0, stream>>>(Wf, Wi, Wc, Wo, Wt);

  lstm_fused<<<dim3(4096), dim3(256), SMEM_BYTES, stream>>>(
      x, hprev, cprev, Wt, bfp, bip, bcp, bop,
      out, out + (size_t)BATCH * UNITS);
}